// Round 8
// baseline (337.436 us; speedup 1.0000x reference)
//
#include <hip/hip_runtime.h>
#include <hip/hip_bf16.h>
#include <cstdint>
#include <cstddef>

// CausalSelfAttention: B=4, T=2048, C=1024, H=16, hs=64 (fp32 in/out, bf16 MFMA compute)
//
// Pipeline: x->bf16 | W^T bf16 | GEMM1 (qkv) | V-transpose | flash attn | GEMM2
//
// Workspace layout (96 MiB):
//   [0,16M)   x_bf16 (GEMM1 input), then Vt[b][h][64][2048] (attn input)
//   [16M,22M) W_attn^T bf16
//   [24M,26M) W_proj^T bf16
//   [32M,80M) qkv bf16      (8192 x 3072)
//   [80M,96M) y bf16        (8192 x 1024)

typedef unsigned short ushort_t;
typedef __attribute__((ext_vector_type(8))) short short8;
typedef __attribute__((ext_vector_type(4))) float f32x4;

#define AS1 __attribute__((address_space(1)))
#define AS3 __attribute__((address_space(3)))

#if __has_builtin(__builtin_amdgcn_exp2f)
#define EXP2(x) __builtin_amdgcn_exp2f(x)
#else
#define EXP2(x) exp2f(x)
#endif

__device__ __forceinline__ ushort_t f2bf(float f) {
  union { float f; unsigned u; } c; c.f = f;
  unsigned u = c.u;
  return (ushort_t)((u + 0x7FFFu + ((u >> 16) & 1u)) >> 16);  // RNE
}

// v_cvt_pk_bf16_f32: lo16 = bf16(a), hi16 = bf16(b)
__device__ __forceinline__ unsigned cvt_pk_bf16(float a, float b) {
  unsigned r;
  asm("v_cvt_pk_bf16_f32 %0, %1, %2" : "=v"(r) : "v"(a), "v"(b));
  return r;
}

// ---------------- fp32 -> bf16 elementwise (8 elems/thread) ----------------
__global__ __launch_bounds__(256) void k_f32_to_bf16(const float* __restrict__ in,
                                                     ushort_t* __restrict__ out) {
  const size_t i = ((size_t)blockIdx.x * 256 + threadIdx.x) * 8;
  f32x4 a = *(const f32x4*)(in + i);
  f32x4 b = *(const f32x4*)(in + i + 4);
  short8 o;
  o[0] = (short)f2bf(a[0]); o[1] = (short)f2bf(a[1]);
  o[2] = (short)f2bf(a[2]); o[3] = (short)f2bf(a[3]);
  o[4] = (short)f2bf(b[0]); o[5] = (short)f2bf(b[1]);
  o[6] = (short)f2bf(b[2]); o[7] = (short)f2bf(b[3]);
  *(short8*)(out + i) = o;
}

// ------------- fp32 (R x C) -> bf16 transposed (C x R), LDS-tiled ----------
__global__ __launch_bounds__(256) void k_transpose_bf16(const float* __restrict__ in,
                                                        ushort_t* __restrict__ out,
                                                        int R, int C) {
  __shared__ float tile[32][33];
  const int tx = threadIdx.x & 31, ty = threadIdx.x >> 5;  // 32x8
  const int c0 = blockIdx.x * 32, r0 = blockIdx.y * 32;
#pragma unroll
  for (int i = 0; i < 32; i += 8)
    tile[ty + i][tx] = in[(size_t)(r0 + ty + i) * C + c0 + tx];
  __syncthreads();
#pragma unroll
  for (int i = 0; i < 32; i += 8)
    out[(size_t)(c0 + ty + i) * R + r0 + tx] = f2bf(tile[tx][ty + i]);
}

// ---- V transpose: qkv V-section (t-major) -> Vt[b][h][d][t] (key-major) ----
__global__ __launch_bounds__(256) void k_vt(const ushort_t* __restrict__ qkv,
                                            ushort_t* __restrict__ vt) {
  __shared__ ushort_t tl[64][72];
  const int T = 2048, C3 = 3072;
  const int t0 = blockIdx.x * 64, h = blockIdx.y, b = blockIdx.z;
  const int r = threadIdx.x >> 4;         // 0..15
  const int c4 = (threadIdx.x & 15) * 4;  // 0..60
  const ushort_t* src = qkv + (size_t)(b * T + t0) * C3 + 2048 + h * 64;
#pragma unroll
  for (int p = 0; p < 4; p++) {
    const int row = p * 16 + r;
    *(short4*)&tl[row][c4] = *(const short4*)(src + (size_t)row * C3 + c4);
  }
  __syncthreads();
  ushort_t* dst = vt + (size_t)((b * 16 + h) * 64) * T + t0;
#pragma unroll
  for (int p = 0; p < 4; p++) {
    const int d = p * 16 + r;
    short4 o;
    o.x = (short)tl[c4 + 0][d];
    o.y = (short)tl[c4 + 1][d];
    o.z = (short)tl[c4 + 2][d];
    o.w = (short)tl[c4 + 3][d];
    *(short4*)(dst + (size_t)d * T + c4) = o;
  }
}

// ---------------- bf16 GEMM: C[M,N] = A[M,K] * Bt[N,K]^T -------------------
template <bool OUT_BF16>
__global__ __launch_bounds__(256) void k_gemm_bt(const ushort_t* __restrict__ A,
                                                 const ushort_t* __restrict__ Bt,
                                                 void* __restrict__ Cout,
                                                 int N, int K) {
  __shared__ ushort_t As[128 * 64];
  __shared__ ushort_t Bs[128 * 64];
  const int tid = threadIdx.x;
  const int wave = tid >> 6, lane = tid & 63;
  const int c = lane & 15, g = lane >> 4;
  const int wm = wave >> 1, wn = wave & 1;
  const int bx = blockIdx.x, by = blockIdx.y;

  f32x4 acc[4][4];
#pragma unroll
  for (int m = 0; m < 4; m++)
#pragma unroll
    for (int n = 0; n < 4; n++) acc[m][n] = (f32x4){0.f, 0.f, 0.f, 0.f};

  for (int k0 = 0; k0 < K; k0 += 64) {
#pragma unroll
    for (int i = 0; i < 4; i++) {
      const int flat = i * 256 + tid;
      const ushort_t* srcA = A + (size_t)(by * 128 + (flat >> 3)) * K + k0 + (flat & 7) * 8;
      const ushort_t* srcB = Bt + (size_t)(bx * 128 + (flat >> 3)) * K + k0 + (flat & 7) * 8;
      const int ldsoff = (i * 256 + wave * 64) * 16;
      __builtin_amdgcn_global_load_lds((const AS1 void*)srcA,
                                       (AS3 void*)((char*)As + ldsoff), 16, 0, 0);
      __builtin_amdgcn_global_load_lds((const AS1 void*)srcB,
                                       (AS3 void*)((char*)Bs + ldsoff), 16, 0, 0);
    }
    __syncthreads();
#pragma unroll
    for (int kk = 0; kk < 2; kk++) {
      short8 af[4], bfr[4];
#pragma unroll
      for (int m = 0; m < 4; m++)
        af[m] = *(const short8*)(As + (wm * 64 + m * 16 + c) * 64 + kk * 32 + g * 8);
#pragma unroll
      for (int n = 0; n < 4; n++)
        bfr[n] = *(const short8*)(Bs + (wn * 64 + n * 16 + c) * 64 + kk * 32 + g * 8);
#pragma unroll
      for (int m = 0; m < 4; m++)
#pragma unroll
        for (int n = 0; n < 4; n++)
          acc[m][n] = __builtin_amdgcn_mfma_f32_16x16x32_bf16(af[m], bfr[n], acc[m][n], 0, 0, 0);
    }
    __syncthreads();
  }

#pragma unroll
  for (int m = 0; m < 4; m++)
#pragma unroll
    for (int n = 0; n < 4; n++) {
      const int col = bx * 128 + wn * 64 + n * 16 + c;
#pragma unroll
      for (int r = 0; r < 4; r++) {
        const int row = by * 128 + wm * 64 + m * 16 + g * 4 + r;
        if (OUT_BF16)
          ((ushort_t*)Cout)[(size_t)row * N + col] = f2bf(acc[m][n][r]);
        else
          ((float*)Cout)[(size_t)row * N + col] = acc[m][n][r];
      }
    }
}

// ---------------- flash attention, causal, hs=64 ----------------------------
// Grid (16, H, B), 256 threads: block = 128 q-rows (4 waves x 32), 64-key
// tiles, 4 independent blocks/CU (launch_bounds(256,4), 40KB LDS) so each
// SIMD carries 4 waves with INDEPENDENT barriers — cross-block overlap hides
// the per-tile dependency chain that R3/R7 exposed.
// S^T = K*Q^T, y^T = V^T*P^T: softmax state at q = lane&15.
// P redistribution via per-wave 2KB LDS round-trip (no barrier needed),
// replacing 32 ds_bpermute per tile.

// Stage one 64x64 bf16 tile pair into LDS. LDS row r (128B) holds global
// 16B-block u at slot u^(r&7); reads apply byte ^= ((r&7)<<4).
__device__ __forceinline__ void stage_kv(const ushort_t* __restrict__ Kp,
                                         const ushort_t* __restrict__ Vt,
                                         ushort_t* Kl, ushort_t* Vl,
                                         int kb, int wave, int lane) {
  const int C3 = 3072, T = 2048;
#pragma unroll
  for (int j = 0; j < 2; j++) {
    const int rbase = wave * 16 + j * 8;
    const int r = rbase + (lane >> 3);
    const int cbg = ((lane & 7) ^ (r & 7)) << 4;  // pre-swizzled global byte col
    const int ldsbase = rbase * 128;               // + lane*16 implicit
    __builtin_amdgcn_global_load_lds(
        (const AS1 void*)(Kp + (size_t)(kb + r) * C3 + (cbg >> 1)),
        (AS3 void*)((char*)Kl + ldsbase), 16, 0, 0);
    __builtin_amdgcn_global_load_lds(
        (const AS1 void*)(Vt + (size_t)r * T + kb + (cbg >> 1)),
        (AS3 void*)((char*)Vl + ldsbase), 16, 0, 0);
  }
}

__global__ __launch_bounds__(256, 4) void k_attn(const ushort_t* __restrict__ qkv,
                                                 const ushort_t* __restrict__ vt,
                                                 ushort_t* __restrict__ y) {
  const int T = 2048, C3 = 3072, Cc = 1024;
  __shared__ ushort_t Kl[2][64 * 64];
  __shared__ ushort_t Vl[2][64 * 64];
  __shared__ ushort_t Pl[4][1024];  // per-wave P tile: 16 q x 64 keys, swizzled

  const int tid = threadIdx.x;
  const int wave = tid >> 6, lane = tid & 63;
  const int c = lane & 15, g = lane >> 4;
  const int b = blockIdx.z, h = blockIdx.y;
  const int qi = 15 - blockIdx.x;  // heavy blocks first (LPT schedule)
  const int qbase = qi * 128 + wave * 32;

  const size_t base = (size_t)b * T * C3 + h * 64;
  const ushort_t* Q = qkv + base;
  const ushort_t* Kp = qkv + base + 1024;
  const ushort_t* Vt = vt + (size_t)((b * 16 + h) * 64) * T;

  const float KS = 0.125f * 1.44269504f;  // 1/sqrt(64) * log2(e)
  const float THR = 8.0f;                 // defer-max threshold (exp2 units)

  // Q^T B-fragments: lane holds Q[qbase+f*16+c][kk*32+g*8 .. +8]
  short8 qf[2][2];
#pragma unroll
  for (int f = 0; f < 2; f++) {
    const ushort_t* qp = Q + (size_t)(qbase + f * 16 + c) * C3 + g * 8;
    qf[f][0] = *(const short8*)qp;
    qf[f][1] = *(const short8*)(qp + 32);
  }

  f32x4 yacc[2][4];
#pragma unroll
  for (int f = 0; f < 2; f++)
#pragma unroll
    for (int dc = 0; dc < 4; dc++) yacc[f][dc] = (f32x4){0.f, 0.f, 0.f, 0.f};
  float mx[2] = {-3.0e38f, -3.0e38f};
  float ssum[2] = {0.f, 0.f};
  const int psw = (c & 7) << 4;  // P_lds row swizzle

  const int nk_blk = (qi + 1) * 128;  // block-uniform trip count
  stage_kv(Kp, Vt, Kl[0], Vl[0], 0, wave, lane);
  __syncthreads();
  int cur = 0;

  for (int kb = 0; kb < nk_blk; kb += 64) {
    if (kb + 64 < nk_blk)
      stage_kv(Kp, Vt, Kl[cur ^ 1], Vl[cur ^ 1], kb + 64, wave, lane);

    if (kb < qbase + 32) {  // wave-uniform: this wave has live rows in tile
      const char* Kbuf = (const char*)Kl[cur];
      const char* Vbuf = (const char*)Vl[cur];

      // K A-fragments from LDS (f-invariant): K[kb+sub*16+c][kk*32+g*8]
      short8 kf[4][2];
#pragma unroll
      for (int sub = 0; sub < 4; sub++) {
        const int r = sub * 16 + c;
        const int sw = (r & 7) << 4;
#pragma unroll
        for (int kk = 0; kk < 2; kk++)
          kf[sub][kk] = *(const short8*)(Kbuf + r * 128 + ((kk * 64 + g * 16) ^ sw));
      }

#pragma unroll
      for (int f = 0; f < 2; f++) {
        f32x4 s[4];
        const f32x4 z = (f32x4){0.f, 0.f, 0.f, 0.f};
#pragma unroll
        for (int sub = 0; sub < 4; sub++) {
          s[sub] = __builtin_amdgcn_mfma_f32_16x16x32_bf16(kf[sub][0], qf[f][0], z, 0, 0, 0);
          s[sub] = __builtin_amdgcn_mfma_f32_16x16x32_bf16(kf[sub][1], qf[f][1], s[sub], 0, 0, 0);
        }

        float sv[16];
#pragma unroll
        for (int sub = 0; sub < 4; sub++)
#pragma unroll
          for (int r = 0; r < 4; r++) sv[sub * 4 + r] = s[sub][r];

        const int q = qbase + f * 16 + c;
        if (kb + 63 > qbase + f * 16) {  // diagonal: causal mask
#pragma unroll
          for (int j = 0; j < 16; j++) {
            const int key = kb + (j >> 2) * 16 + g * 4 + (j & 3);
            if (key > q) sv[j] = -1.0e30f;
          }
        }

        // ---- online softmax at q = lane&15, tree-shaped reductions ----
        float t8[8], t4[4];
#pragma unroll
        for (int j = 0; j < 8; j++) t8[j] = fmaxf(sv[j], sv[j + 8]);
#pragma unroll
        for (int j = 0; j < 4; j++) t4[j] = fmaxf(t8[j], t8[j + 4]);
        float tm = fmaxf(fmaxf(t4[0], t4[1]), fmaxf(t4[2], t4[3]));
        tm = fmaxf(tm, __shfl_xor(tm, 16));
        tm = fmaxf(tm, __shfl_xor(tm, 32));
        const float cand = tm * KS;

        if (__any(cand > mx[f] + THR)) {  // rescale path (defer-max, T13)
          const float mnew = fmaxf(mx[f], cand);
          const float alpha = EXP2(mx[f] - mnew);
          ssum[f] *= alpha;
#pragma unroll
          for (int dc = 0; dc < 4; dc++)
#pragma unroll
            for (int r = 0; r < 4; r++) yacc[f][dc][r] *= alpha;
          mx[f] = mnew;
        }

        float p[16];
#pragma unroll
        for (int j = 0; j < 16; j++)
          p[j] = EXP2(__builtin_fmaf(sv[j], KS, -mx[f]));
        float s8[8], s4[4];
#pragma unroll
        for (int j = 0; j < 8; j++) s8[j] = p[j] + p[j + 8];
#pragma unroll
        for (int j = 0; j < 4; j++) s4[j] = s8[j] + s8[j + 4];
        float ts = (s4[0] + s4[1]) + (s4[2] + s4[3]);
        ts += __shfl_xor(ts, 16);
        ts += __shfl_xor(ts, 32);
        ssum[f] += ts;

        // ---- P -> LDS (adjacent-key bf16 pairs), wave-local ----
        // write key sub*16+g*4+{0..3} at byte c*128 + ((sub*32+g*8)^psw)
        ushort_t* Pw = &Pl[wave][0];
#pragma unroll
        for (int sub = 0; sub < 4; sub++) {
          uint2 w2;
          w2.x = cvt_pk_bf16(p[sub * 4 + 0], p[sub * 4 + 1]);
          w2.y = cvt_pk_bf16(p[sub * 4 + 2], p[sub * 4 + 3]);
          *(uint2*)&Pw[(c * 128 + ((sub * 32 + g * 8) ^ psw)) >> 1] = w2;
        }

        // ---- PV: read pf + V frags, MFMA ----
#pragma unroll
        for (int hh = 0; hh < 2; hh++) {
          // pf[r] = P[q=c][key = kb + hh*32 + g*8 + r]
          const short8 pf = *(const short8*)&Pw[(c * 128 + ((hh * 64 + g * 16) ^ psw)) >> 1];
          short8 vf[4];
#pragma unroll
          for (int dc = 0; dc < 4; dc++) {
            const int r = dc * 16 + c;
            const int sw = (r & 7) << 4;
            vf[dc] = *(const short8*)(Vbuf + r * 128 + ((hh * 64 + g * 16) ^ sw));
          }
#pragma unroll
          for (int dc = 0; dc < 4; dc++)
            yacc[f][dc] = __builtin_amdgcn_mfma_f32_16x16x32_bf16(vf[dc], pf, yacc[f][dc], 0, 0, 0);
        }
      }
    }

    __syncthreads();  // drains vmcnt: next tile staged, this tile's reads done
    cur ^= 1;
  }

  // normalize + packed store (short4), per q-fragment
#pragma unroll
  for (int f = 0; f < 2; f++) {
    const float inv = 1.0f / ssum[f];
    const int q = qbase + f * 16 + c;
    ushort_t* yp = y + (size_t)(b * T + q) * Cc + h * 64;
#pragma unroll
    for (int dc = 0; dc < 4; dc++) {
      short4 o;
      o.x = (short)f2bf(yacc[f][dc][0] * inv);
      o.y = (short)f2bf(yacc[f][dc][1] * inv);
      o.z = (short)f2bf(yacc[f][dc][2] * inv);
      o.w = (short)f2bf(yacc[f][dc][3] * inv);
      *(short4*)(yp + dc * 16 + g * 4) = o;
    }
  }
}

// ---------------------------------------------------------------------------
extern "C" void kernel_launch(void* const* d_in, const int* in_sizes, int n_in,
                              void* d_out, int out_size, void* d_ws, size_t ws_size,
                              hipStream_t stream) {
  const float* x = (const float*)d_in[0];     // (4, 2048, 1024)
  const float* Wat = (const float*)d_in[1];   // (1024, 3072)
  const float* Wpr = (const float*)d_in[2];   // (1024, 1024)
  float* out = (float*)d_out;                 // (4, 2048, 1024)

  const int T = 2048, B = 4, H = 16, Cc = 1024;
  const int M = B * T;  // 8192

  char* ws = (char*)d_ws;
  const size_t MB = 1024 * 1024;
  ushort_t* xb = (ushort_t*)ws;                 // 16 MB (x_bf16, then Vt)
  ushort_t* wat = (ushort_t*)(ws + 16 * MB);    // 6 MB
  ushort_t* wpt = (ushort_t*)(ws + 24 * MB);    // 2 MB
  ushort_t* qkv = (ushort_t*)(ws + 32 * MB);    // 48 MB
  ushort_t* yb = (ushort_t*)(ws + 80 * MB);     // 16 MB
  ushort_t* vtb = xb;                           // reuse after GEMM1

  // 1. convert inputs to bf16 (weights transposed to [N][K])
  k_f32_to_bf16<<<dim3((M * Cc) / (8 * 256)), 256, 0, stream>>>(x, xb);
  k_transpose_bf16<<<dim3(3072 / 32, 1024 / 32), 256, 0, stream>>>(Wat, wat, 1024, 3072);
  k_transpose_bf16<<<dim3(1024 / 32, 1024 / 32), 256, 0, stream>>>(Wpr, wpt, 1024, 1024);

  // 2. qkv = x @ W_attn   (8192 x 3072)
  k_gemm_bt<true><<<dim3(3072 / 128, M / 128), 256, 0, stream>>>(xb, wat, qkv, 3072, 1024);

  // 3. V -> Vt[b][h][d][t]  (xb region is dead now)
  k_vt<<<dim3(T / 64, H, B), 256, 0, stream>>>(qkv, vtb);

  // 4. causal flash attention -> y (8192 x 1024 bf16)
  k_attn<<<dim3(16, H, B), 256, 0, stream>>>(qkv, vtb, yb);

  // 5. out = y @ W_proj   (8192 x 1024, fp32)
  k_gemm_bt<false><<<dim3(1024 / 128, M / 128), 256, 0, stream>>>(yb, wpt, out, 1024, 1024);
}

// Round 10
// 226.796 us; speedup vs baseline: 1.4878x; 1.4878x over previous
//
#include <hip/hip_runtime.h>
#include <hip/hip_bf16.h>
#include <cstdint>
#include <cstddef>

// CausalSelfAttention: B=4, T=2048, C=1024, H=16, hs=64 (fp32 in/out, bf16 MFMA compute)
//
// Pipeline: x->bf16 | W^T bf16 | GEMM1 (qkv) | V-transpose | flash attn | GEMM2
//
// Workspace layout (96 MiB):
//   [0,16M)   x_bf16 (GEMM1 input), then Vt[b][h][64][2048] (attn input)
//   [16M,22M) W_attn^T bf16
//   [24M,26M) W_proj^T bf16
//   [32M,80M) qkv bf16      (8192 x 3072)
//   [80M,96M) y bf16        (8192 x 1024)

typedef unsigned short ushort_t;
typedef __attribute__((ext_vector_type(8))) short short8;
typedef __attribute__((ext_vector_type(4))) float f32x4;
typedef __attribute__((ext_vector_type(16))) float f32x16;

#define AS1 __attribute__((address_space(1)))
#define AS3 __attribute__((address_space(3)))

#if __has_builtin(__builtin_amdgcn_exp2f)
#define EXP2(x) __builtin_amdgcn_exp2f(x)
#else
#define EXP2(x) exp2f(x)
#endif

__device__ __forceinline__ ushort_t f2bf(float f) {
  union { float f; unsigned u; } c; c.f = f;
  unsigned u = c.u;
  return (ushort_t)((u + 0x7FFFu + ((u >> 16) & 1u)) >> 16);  // RNE
}

// v_cvt_pk_bf16_f32: lo16 = bf16(a), hi16 = bf16(b)
__device__ __forceinline__ unsigned cvt_pk_bf16(float a, float b) {
  unsigned r;
  asm("v_cvt_pk_bf16_f32 %0, %1, %2" : "=v"(r) : "v"(a), "v"(b));
  return r;
}

// ---------------- fp32 -> bf16 elementwise (8 elems/thread) ----------------
__global__ __launch_bounds__(256) void k_f32_to_bf16(const float* __restrict__ in,
                                                     ushort_t* __restrict__ out) {
  const size_t i = ((size_t)blockIdx.x * 256 + threadIdx.x) * 8;
  f32x4 a = *(const f32x4*)(in + i);
  f32x4 b = *(const f32x4*)(in + i + 4);
  short8 o;
  o[0] = (short)f2bf(a[0]); o[1] = (short)f2bf(a[1]);
  o[2] = (short)f2bf(a[2]); o[3] = (short)f2bf(a[3]);
  o[4] = (short)f2bf(b[0]); o[5] = (short)f2bf(b[1]);
  o[6] = (short)f2bf(b[2]); o[7] = (short)f2bf(b[3]);
  *(short8*)(out + i) = o;
}

// ------------- fp32 (R x C) -> bf16 transposed (C x R), LDS-tiled ----------
__global__ __launch_bounds__(256) void k_transpose_bf16(const float* __restrict__ in,
                                                        ushort_t* __restrict__ out,
                                                        int R, int C) {
  __shared__ float tile[32][33];
  const int tx = threadIdx.x & 31, ty = threadIdx.x >> 5;  // 32x8
  const int c0 = blockIdx.x * 32, r0 = blockIdx.y * 32;
#pragma unroll
  for (int i = 0; i < 32; i += 8)
    tile[ty + i][tx] = in[(size_t)(r0 + ty + i) * C + c0 + tx];
  __syncthreads();
#pragma unroll
  for (int i = 0; i < 32; i += 8)
    out[(size_t)(c0 + ty + i) * R + r0 + tx] = f2bf(tile[tx][ty + i]);
}

// ---- V transpose: qkv V-section (t-major) -> Vt[b][h][d][t] (key-major) ----
__global__ __launch_bounds__(256) void k_vt(const ushort_t* __restrict__ qkv,
                                            ushort_t* __restrict__ vt) {
  __shared__ ushort_t tl[64][72];
  const int T = 2048, C3 = 3072;
  const int t0 = blockIdx.x * 64, h = blockIdx.y, b = blockIdx.z;
  const int r = threadIdx.x >> 4;         // 0..15
  const int c4 = (threadIdx.x & 15) * 4;  // 0..60
  const ushort_t* src = qkv + (size_t)(b * T + t0) * C3 + 2048 + h * 64;
#pragma unroll
  for (int p = 0; p < 4; p++) {
    const int row = p * 16 + r;
    *(short4*)&tl[row][c4] = *(const short4*)(src + (size_t)row * C3 + c4);
  }
  __syncthreads();
  ushort_t* dst = vt + (size_t)((b * 16 + h) * 64) * T + t0;
#pragma unroll
  for (int p = 0; p < 4; p++) {
    const int d = p * 16 + r;
    short4 o;
    o.x = (short)tl[c4 + 0][d];
    o.y = (short)tl[c4 + 1][d];
    o.z = (short)tl[c4 + 2][d];
    o.w = (short)tl[c4 + 3][d];
    *(short4*)(dst + (size_t)d * T + c4) = o;
  }
}

// ---------------- bf16 GEMM: C[M,N] = A[M,K] * Bt[N,K]^T -------------------
template <bool OUT_BF16>
__global__ __launch_bounds__(256) void k_gemm_bt(const ushort_t* __restrict__ A,
                                                 const ushort_t* __restrict__ Bt,
                                                 void* __restrict__ Cout,
                                                 int N, int K) {
  __shared__ ushort_t As[128 * 64];
  __shared__ ushort_t Bs[128 * 64];
  const int tid = threadIdx.x;
  const int wave = tid >> 6, lane = tid & 63;
  const int c = lane & 15, g = lane >> 4;
  const int wm = wave >> 1, wn = wave & 1;
  const int bx = blockIdx.x, by = blockIdx.y;

  f32x4 acc[4][4];
#pragma unroll
  for (int m = 0; m < 4; m++)
#pragma unroll
    for (int n = 0; n < 4; n++) acc[m][n] = (f32x4){0.f, 0.f, 0.f, 0.f};

  for (int k0 = 0; k0 < K; k0 += 64) {
#pragma unroll
    for (int i = 0; i < 4; i++) {
      const int flat = i * 256 + tid;
      const ushort_t* srcA = A + (size_t)(by * 128 + (flat >> 3)) * K + k0 + (flat & 7) * 8;
      const ushort_t* srcB = Bt + (size_t)(bx * 128 + (flat >> 3)) * K + k0 + (flat & 7) * 8;
      const int ldsoff = (i * 256 + wave * 64) * 16;
      __builtin_amdgcn_global_load_lds((const AS1 void*)srcA,
                                       (AS3 void*)((char*)As + ldsoff), 16, 0, 0);
      __builtin_amdgcn_global_load_lds((const AS1 void*)srcB,
                                       (AS3 void*)((char*)Bs + ldsoff), 16, 0, 0);
    }
    __syncthreads();
#pragma unroll
    for (int kk = 0; kk < 2; kk++) {
      short8 af[4], bfr[4];
#pragma unroll
      for (int m = 0; m < 4; m++)
        af[m] = *(const short8*)(As + (wm * 64 + m * 16 + c) * 64 + kk * 32 + g * 8);
#pragma unroll
      for (int n = 0; n < 4; n++)
        bfr[n] = *(const short8*)(Bs + (wn * 64 + n * 16 + c) * 64 + kk * 32 + g * 8);
#pragma unroll
      for (int m = 0; m < 4; m++)
#pragma unroll
        for (int n = 0; n < 4; n++)
          acc[m][n] = __builtin_amdgcn_mfma_f32_16x16x32_bf16(af[m], bfr[n], acc[m][n], 0, 0, 0);
    }
    __syncthreads();
  }

#pragma unroll
  for (int m = 0; m < 4; m++)
#pragma unroll
    for (int n = 0; n < 4; n++) {
      const int col = bx * 128 + wn * 64 + n * 16 + c;
#pragma unroll
      for (int r = 0; r < 4; r++) {
        const int row = by * 128 + wm * 64 + m * 16 + g * 4 + r;
        if (OUT_BF16)
          ((ushort_t*)Cout)[(size_t)row * N + col] = f2bf(acc[m][n][r]);
        else
          ((float*)Cout)[(size_t)row * N + col] = acc[m][n][r];
      }
    }
}

// ---------------- flash attention, causal, hs=64 ----------------------------
// Grid (16, H, B), 4 waves x 32 q-rows, 64-key tiles, 32x32x16 MFMA.
// S^T = K*Q^T in 32x32 layout: lane owns q = lane&31; hi = lane>>5 selects
// which key sub-slice the lane's regs hold. Softmax: in-register tree + ONE
// shfl_xor(32). P -> PV B-fragment: cvt_pk pairs + half-exchange via
// shfl_xor(32) + cndmask (derivation-safe, no permlane direction assumption).
// K/V tiles LDS-staged (global_load_lds, XOR-swizzled), double-buffered.

// Stage one 64x64 bf16 tile pair into LDS. LDS row r (128B) holds global
// 16B-block u at slot u^(r&7); reads apply byte ^= ((r&7)<<4).
__device__ __forceinline__ void stage_kv(const ushort_t* __restrict__ Kp,
                                         const ushort_t* __restrict__ Vt,
                                         ushort_t* Kl, ushort_t* Vl,
                                         int kb, int wave, int lane) {
  const int C3 = 3072, T = 2048;
#pragma unroll
  for (int j = 0; j < 2; j++) {
    const int rbase = wave * 16 + j * 8;
    const int r = rbase + (lane >> 3);
    const int cbg = ((lane & 7) ^ (r & 7)) << 4;  // pre-swizzled global byte col
    const int ldsbase = rbase * 128;               // + lane*16 implicit
    __builtin_amdgcn_global_load_lds(
        (const AS1 void*)(Kp + (size_t)(kb + r) * C3 + (cbg >> 1)),
        (AS3 void*)((char*)Kl + ldsbase), 16, 0, 0);
    __builtin_amdgcn_global_load_lds(
        (const AS1 void*)(Vt + (size_t)r * T + kb + (cbg >> 1)),
        (AS3 void*)((char*)Vl + ldsbase), 16, 0, 0);
  }
}

__global__ __launch_bounds__(256, 2) void k_attn(const ushort_t* __restrict__ qkv,
                                                 const ushort_t* __restrict__ vt,
                                                 ushort_t* __restrict__ y) {
  const int T = 2048, C3 = 3072, Cc = 1024;
  __shared__ ushort_t Kl[2][64 * 64];
  __shared__ ushort_t Vl[2][64 * 64];

  const int tid = threadIdx.x;
  const int wave = tid >> 6, lane = tid & 63;
  const int l31 = lane & 31, hi = lane >> 5;
  const bool hib = (hi != 0);
  const int swr = (l31 & 7) << 4;  // LDS read swizzle for rows l31, 32+l31
  const int b = blockIdx.z, h = blockIdx.y;
  const int qi = 15 - blockIdx.x;  // heavy blocks first (LPT schedule)
  const int qbase = qi * 128 + wave * 32;
  const int q = qbase + l31;

  const size_t base = (size_t)b * T * C3 + h * 64;
  const ushort_t* Q = qkv + base;
  const ushort_t* Kp = qkv + base + 1024;
  const ushort_t* Vt = vt + (size_t)((b * 16 + h) * 64) * T;

  const float KS = 0.125f * 1.44269504f;  // 1/sqrt(64) * log2(e)
  const float THR = 8.0f;                 // defer-max threshold (exp2 units)

  // Q^T B-fragments: B[k=16i+8hi+r][q=l31] = Q[q][16i+8hi+r]
  short8 qfr[4];
  {
    const ushort_t* qp = Q + (size_t)q * C3 + 8 * hi;
#pragma unroll
    for (int i = 0; i < 4; i++) qfr[i] = *(const short8*)(qp + 16 * i);
  }

  f32x16 yacc0 = (f32x16)(0.0f), yacc1 = (f32x16)(0.0f);  // d-halves 0..31, 32..63
  float mx = -3.0e38f, ssum = 0.f;

  const int nk_blk = (qi + 1) * 128;  // block-uniform trip count
  stage_kv(Kp, Vt, Kl[0], Vl[0], 0, wave, lane);
  __syncthreads();
  int cur = 0;

  for (int kb = 0; kb < nk_blk; kb += 64) {
    if (kb + 64 < nk_blk)
      stage_kv(Kp, Vt, Kl[cur ^ 1], Vl[cur ^ 1], kb + 64, wave, lane);

    if (kb < qbase + 32) {  // wave-uniform: this wave has live rows in tile
      const char* Kbuf = (const char*)Kl[cur];
      const char* Vbuf = (const char*)Vl[cur];

      // ---- QK^T: S^T[key][q], two 32-key sub-blocks ----
      f32x16 s0 = (f32x16)(0.0f), s1 = (f32x16)(0.0f);
#pragma unroll
      for (int i = 0; i < 4; i++) {
        const int colb = (32 * i + 16 * hi) ^ swr;
        const short8 ka0 = *(const short8*)(Kbuf + l31 * 128 + colb);
        const short8 ka1 = *(const short8*)(Kbuf + (32 + l31) * 128 + colb);
        s0 = __builtin_amdgcn_mfma_f32_32x32x16_bf16(ka0, qfr[i], s0, 0, 0, 0);
        s1 = __builtin_amdgcn_mfma_f32_32x32x16_bf16(ka1, qfr[i], s1, 0, 0, 0);
      }

      // ---- causal mask (raw scores; key = kb + sub*32 + (r&3)+8*(r>>2)+4hi) ----
      if (kb + 63 > qbase) {
#pragma unroll
        for (int r = 0; r < 16; r++) {
          const int key = kb + (r & 3) + 8 * (r >> 2) + 4 * hi;
          if (key > q) s0[r] = -1.0e30f;
          if (key + 32 > q) s1[r] = -1.0e30f;
        }
      }

      // ---- online softmax for q = l31 (one cross-half exchange) ----
      float t16[16];
#pragma unroll
      for (int r = 0; r < 16; r++) t16[r] = fmaxf(s0[r], s1[r]);
#pragma unroll
      for (int r = 0; r < 8; r++) t16[r] = fmaxf(t16[r], t16[r + 8]);
#pragma unroll
      for (int r = 0; r < 4; r++) t16[r] = fmaxf(t16[r], t16[r + 4]);
      float tm = fmaxf(fmaxf(t16[0], t16[1]), fmaxf(t16[2], t16[3]));
      tm = fmaxf(tm, __shfl_xor(tm, 32));
      const float cand = tm * KS;

      if (__any(cand > mx + THR)) {  // defer-max rescale (T13)
        const float mnew = fmaxf(mx, cand);
        const float alpha = EXP2(mx - mnew);
        ssum *= alpha;
#pragma unroll
        for (int r = 0; r < 16; r++) { yacc0[r] *= alpha; yacc1[r] *= alpha; }
        mx = mnew;
      }

      // p overwrites s in place (VGPR relief)
#pragma unroll
      for (int r = 0; r < 16; r++) {
        s0[r] = EXP2(__builtin_fmaf(s0[r], KS, -mx));
        s1[r] = EXP2(__builtin_fmaf(s1[r], KS, -mx));
      }
      {
        float ss[16];
#pragma unroll
        for (int r = 0; r < 16; r++) ss[r] = s0[r] + s1[r];
#pragma unroll
        for (int r = 0; r < 8; r++) ss[r] += ss[r + 8];
#pragma unroll
        for (int r = 0; r < 4; r++) ss[r] += ss[r + 4];
        float ts = (ss[0] + ss[1]) + (ss[2] + ss[3]);
        ts += __shfl_xor(ts, 32);
        ssum += ts;
      }

      // ---- P -> bf16 pairs, then half-exchange -> P^T B-fragments ----
      // Lane (l31,hi) holds P[q=l31][key = (r&3)+8*(r>>2)+4hi (+32 for s1)].
      // Chunk j (keys 16j..16j+15) B-frag element r needs key 16j+8hi+r.
      //   hi=0 owns keys {0..3,8..11}+16j  -> words d0,d1 (keys 16j+0..3),
      //                                       d2,d3 (keys 16j+8..11)
      //   hi=1 owns keys {4..7,12..15}+16j -> d0,d1 = 16j+4..7, d2,d3 = +12..15
      // Needed: hi=0: [own d0, own d1, partner d0, partner d1]
      //         hi=1: [partner d2, partner d3, own d2, own d3]
      // snd = hib ? d0 : d2; rcv = shfl_xor(snd,32) delivers exactly those.
      union U4 { unsigned u[4]; short8 v; };
      U4 pb[4];
      {
        unsigned dw[4][4];
#pragma unroll
        for (int j = 0; j < 2; j++) {  // chunks 0,1 from s0
          dw[j][0] = cvt_pk_bf16(s0[j * 8 + 0], s0[j * 8 + 1]);
          dw[j][1] = cvt_pk_bf16(s0[j * 8 + 2], s0[j * 8 + 3]);
          dw[j][2] = cvt_pk_bf16(s0[j * 8 + 4], s0[j * 8 + 5]);
          dw[j][3] = cvt_pk_bf16(s0[j * 8 + 6], s0[j * 8 + 7]);
          dw[2 + j][0] = cvt_pk_bf16(s1[j * 8 + 0], s1[j * 8 + 1]);
          dw[2 + j][1] = cvt_pk_bf16(s1[j * 8 + 2], s1[j * 8 + 3]);
          dw[2 + j][2] = cvt_pk_bf16(s1[j * 8 + 4], s1[j * 8 + 5]);
          dw[2 + j][3] = cvt_pk_bf16(s1[j * 8 + 6], s1[j * 8 + 7]);
        }
#pragma unroll
        for (int j = 0; j < 4; j++) {
          const unsigned d0 = dw[j][0], d1 = dw[j][1], d2 = dw[j][2], d3 = dw[j][3];
          const unsigned snd0 = hib ? d0 : d2;
          const unsigned snd1 = hib ? d1 : d3;
          const unsigned rcv0 = (unsigned)__shfl_xor((int)snd0, 32);
          const unsigned rcv1 = (unsigned)__shfl_xor((int)snd1, 32);
          pb[j].u[0] = hib ? rcv0 : d0;
          pb[j].u[1] = hib ? rcv1 : d1;
          pb[j].u[2] = hib ? d2 : rcv0;
          pb[j].u[3] = hib ? d3 : rcv1;
        }
      }

      // ---- PV: y^T[d][q] += V^T[d][k] * P^T[k][q], k-chunks of 16 keys ----
#pragma unroll
      for (int sj = 0; sj < 4; sj++) {
        const int colb = (sj * 32 + 16 * hi) ^ swr;
        const short8 va0 = *(const short8*)(Vbuf + l31 * 128 + colb);
        const short8 va1 = *(const short8*)(Vbuf + (32 + l31) * 128 + colb);
        yacc0 = __builtin_amdgcn_mfma_f32_32x32x16_bf16(va0, pb[sj].v, yacc0, 0, 0, 0);
        yacc1 = __builtin_amdgcn_mfma_f32_32x32x16_bf16(va1, pb[sj].v, yacc1, 0, 0, 0);
      }
    }

    __syncthreads();  // drains vmcnt: next tile staged, this tile's reads done
    cur ^= 1;
  }

  // ---- normalize + store: d = dh*32 + (r&3)+8*(r>>2)+4hi, q = l31 ----
  const float inv = 1.0f / ssum;
  ushort_t* yp = y + (size_t)(b * T + q) * Cc + h * 64;
#pragma unroll
  for (int gi = 0; gi < 4; gi++) {
    short4 o0, o1;
    o0.x = (short)f2bf(yacc0[gi * 4 + 0] * inv);
    o0.y = (short)f2bf(yacc0[gi * 4 + 1] * inv);
    o0.z = (short)f2bf(yacc0[gi * 4 + 2] * inv);
    o0.w = (short)f2bf(yacc0[gi * 4 + 3] * inv);
    o1.x = (short)f2bf(yacc1[gi * 4 + 0] * inv);
    o1.y = (short)f2bf(yacc1[gi * 4 + 1] * inv);
    o1.z = (short)f2bf(yacc1[gi * 4 + 2] * inv);
    o1.w = (short)f2bf(yacc1[gi * 4 + 3] * inv);
    *(short4*)(yp + 8 * gi + 4 * hi) = o0;
    *(short4*)(yp + 32 + 8 * gi + 4 * hi) = o1;
  }
}

// ---------------------------------------------------------------------------
extern "C" void kernel_launch(void* const* d_in, const int* in_sizes, int n_in,
                              void* d_out, int out_size, void* d_ws, size_t ws_size,
                              hipStream_t stream) {
  const float* x = (const float*)d_in[0];     // (4, 2048, 1024)
  const float* Wat = (const float*)d_in[1];   // (1024, 3072)
  const float* Wpr = (const float*)d_in[2];   // (1024, 1024)
  float* out = (float*)d_out;                 // (4, 2048, 1024)

  const int T = 2048, B = 4, H = 16, Cc = 1024;
  const int M = B * T;  // 8192

  char* ws = (char*)d_ws;
  const size_t MB = 1024 * 1024;
  ushort_t* xb = (ushort_t*)ws;                 // 16 MB (x_bf16, then Vt)
  ushort_t* wat = (ushort_t*)(ws + 16 * MB);    // 6 MB
  ushort_t* wpt = (ushort_t*)(ws + 24 * MB);    // 2 MB
  ushort_t* qkv = (ushort_t*)(ws + 32 * MB);    // 48 MB
  ushort_t* yb = (ushort_t*)(ws + 80 * MB);     // 16 MB
  ushort_t* vtb = xb;                           // reuse after GEMM1

  // 1. convert inputs to bf16 (weights transposed to [N][K])
  k_f32_to_bf16<<<dim3((M * Cc) / (8 * 256)), 256, 0, stream>>>(x, xb);
  k_transpose_bf16<<<dim3(3072 / 32, 1024 / 32), 256, 0, stream>>>(Wat, wat, 1024, 3072);
  k_transpose_bf16<<<dim3(1024 / 32, 1024 / 32), 256, 0, stream>>>(Wpr, wpt, 1024, 1024);

  // 2. qkv = x @ W_attn   (8192 x 3072)
  k_gemm_bt<true><<<dim3(3072 / 128, M / 128), 256, 0, stream>>>(xb, wat, qkv, 3072, 1024);

  // 3. V -> Vt[b][h][d][t]  (xb region is dead now)
  k_vt<<<dim3(T / 64, H, B), 256, 0, stream>>>(qkv, vtb);

  // 4. causal flash attention -> y (8192 x 1024 bf16)
  k_attn<<<dim3(16, H, B), 256, 0, stream>>>(qkv, vtb, yb);

  // 5. out = y @ W_proj   (8192 x 1024, fp32)
  k_gemm_bt<false><<<dim3(1024 / 128, M / 128), 256, 0, stream>>>(yb, wpt, out, 1024, 1024);
}